// Round 1
// baseline (278.421 us; speedup 1.0000x reference)
//
#include <hip/hip_runtime.h>
#include <hip/hip_bf16.h>
#include <cstdint>
#include <cstddef>

typedef __bf16 bf16_t;
typedef __bf16 bf16x8 __attribute__((ext_vector_type(8)));
typedef __bf16 bf16x4 __attribute__((ext_vector_type(4)));
typedef float  f32x4  __attribute__((ext_vector_type(4)));

#define BM 128
#define BN 128
#define BK 64

// ---------------------------------------------------------------------------
// Kernel 1: per-row softmax(mod) + 1, multiply by x, emit bf16.
// One block (256 threads) per row of D=1024; each thread owns 4 elements.
// ---------------------------------------------------------------------------
__global__ void att_scale_kernel(const float* __restrict__ x,
                                 const float* __restrict__ mod,
                                 bf16_t* __restrict__ a, int D) {
  const int b = blockIdx.x;
  const int t = threadIdx.x;
  const size_t row = (size_t)b * D;

  float4 mv = ((const float4*)(mod + row))[t];
  float mx = fmaxf(fmaxf(mv.x, mv.y), fmaxf(mv.z, mv.w));
#pragma unroll
  for (int o = 32; o > 0; o >>= 1) mx = fmaxf(mx, __shfl_xor(mx, o));

  __shared__ float redmax[4];
  __shared__ float redsum[4];
  const int wave = t >> 6, lane = t & 63;
  if (lane == 0) redmax[wave] = mx;
  __syncthreads();
  mx = fmaxf(fmaxf(redmax[0], redmax[1]), fmaxf(redmax[2], redmax[3]));

  float4 e;
  e.x = __expf(mv.x - mx); e.y = __expf(mv.y - mx);
  e.z = __expf(mv.z - mx); e.w = __expf(mv.w - mx);
  float s = (e.x + e.y) + (e.z + e.w);
#pragma unroll
  for (int o = 32; o > 0; o >>= 1) s += __shfl_xor(s, o);
  if (lane == 0) redsum[wave] = s;
  __syncthreads();
  s = (redsum[0] + redsum[1]) + (redsum[2] + redsum[3]);

  const float inv = 1.0f / s;
  float4 xv = ((const float4*)(x + row))[t];
  bf16x4 o4;
  o4[0] = (bf16_t)((e.x * inv + 1.0f) * xv.x);
  o4[1] = (bf16_t)((e.y * inv + 1.0f) * xv.y);
  o4[2] = (bf16_t)((e.z * inv + 1.0f) * xv.z);
  o4[3] = (bf16_t)((e.w * inv + 1.0f) * xv.w);
  *((bf16x4*)(a + row) + t) = o4;
}

// ---------------------------------------------------------------------------
// Kernel 2: fp32 -> bf16 cast of W (C*D elements), 8 per thread.
// ---------------------------------------------------------------------------
__global__ void cast_w_kernel(const float* __restrict__ W,
                              bf16_t* __restrict__ Wb) {
  const size_t i = ((size_t)blockIdx.x * blockDim.x + threadIdx.x) * 8;
  float4 u = *(const float4*)(W + i);
  float4 v = *(const float4*)(W + i + 4);
  bf16x8 o;
  o[0] = (bf16_t)u.x; o[1] = (bf16_t)u.y; o[2] = (bf16_t)u.z; o[3] = (bf16_t)u.w;
  o[4] = (bf16_t)v.x; o[5] = (bf16_t)v.y; o[6] = (bf16_t)v.z; o[7] = (bf16_t)v.w;
  *(bf16x8*)(Wb + i) = o;
}

// ---------------------------------------------------------------------------
// Kernel 3: bf16 GEMM, C[m][n] = sum_k A[m][k] * B[n][k]   (B^T-input GEMM)
// A: (M,K) row-major bf16, B: (N,K) row-major bf16, C: (M,N) fp32.
// m97-ladder structure: 128x128 tile, BK=64, global_load_lds width=16,
// 4 waves in 2x2, each wave computes 64x64 via 4x4 grid of 16x16x32 MFMAs.
// ---------------------------------------------------------------------------
__global__ __launch_bounds__(256) void gemm_bt_kernel(
    const bf16_t* __restrict__ A, const bf16_t* __restrict__ B,
    float* __restrict__ C, int M, int N, int K) {
  __shared__ __align__(16) bf16_t As[BM * BK];  // 16 KB
  __shared__ __align__(16) bf16_t Bs[BN * BK];  // 16 KB

  const int tid  = threadIdx.x;
  const int wave = tid >> 6;
  const int lane = tid & 63;
  const int quad = lane >> 4;
  const int l16  = lane & 15;

  const int m0 = blockIdx.y * BM;
  const int n0 = blockIdx.x * BN;
  const int wm = wave & 1;   // wave row (0..1) -> 64 rows of M
  const int wn = wave >> 1;  // wave col (0..1) -> 64 cols of N

  f32x4 acc[4][4];
#pragma unroll
  for (int i = 0; i < 4; i++)
#pragma unroll
    for (int j = 0; j < 4; j++) acc[i][j] = (f32x4){0.f, 0.f, 0.f, 0.f};

  // staging: 256 threads x 16B = 4KB per instruction; 4 instructions per 16KB tile.
  // thread t, instr i covers linear slot (i*256 + t): row = slot>>3, col8 = slot&7.
  const int rowA = tid >> 3;
  const int col8 = tid & 7;
  const bf16_t* aptr = A + (size_t)(m0 + rowA) * K + col8 * 8;
  const bf16_t* bptr = B + (size_t)(n0 + rowA) * K + col8 * 8;

  for (int k0 = 0; k0 < K; k0 += BK) {
#pragma unroll
    for (int i = 0; i < 4; i++) {
      __builtin_amdgcn_global_load_lds(
          (const __attribute__((address_space(1))) void*)(aptr + (size_t)(i * 32) * K + k0),
          (__attribute__((address_space(3))) void*)(As + (i * 256 + wave * 64) * 8),
          16, 0, 0);
    }
#pragma unroll
    for (int i = 0; i < 4; i++) {
      __builtin_amdgcn_global_load_lds(
          (const __attribute__((address_space(1))) void*)(bptr + (size_t)(i * 32) * K + k0),
          (__attribute__((address_space(3))) void*)(Bs + (i * 256 + wave * 64) * 8),
          16, 0, 0);
    }
    __syncthreads();

#pragma unroll
    for (int kt = 0; kt < 2; kt++) {
      bf16x8 af[4], bf[4];
#pragma unroll
      for (int i = 0; i < 4; i++)
        af[i] = *(const bf16x8*)&As[(wm * 64 + i * 16 + l16) * BK + kt * 32 + quad * 8];
#pragma unroll
      for (int j = 0; j < 4; j++)
        bf[j] = *(const bf16x8*)&Bs[(wn * 64 + j * 16 + l16) * BK + kt * 32 + quad * 8];
#pragma unroll
      for (int i = 0; i < 4; i++)
#pragma unroll
        for (int j = 0; j < 4; j++)
          acc[i][j] = __builtin_amdgcn_mfma_f32_16x16x32_bf16(af[i], bf[j], acc[i][j], 0, 0, 0);
    }
    __syncthreads();
  }

  // Epilogue: C/D layout (16x16): col = lane&15, row = quad*4 + reg.
#pragma unroll
  for (int i = 0; i < 4; i++) {
    const int mg = m0 + wm * 64 + i * 16 + quad * 4;
#pragma unroll
    for (int j = 0; j < 4; j++) {
      const int ng = n0 + wn * 64 + j * 16 + l16;
#pragma unroll
      for (int r = 0; r < 4; r++) {
        C[(size_t)(mg + r) * N + ng] = acc[i][j][r];
      }
    }
  }
}

// ---------------------------------------------------------------------------
extern "C" void kernel_launch(void* const* d_in, const int* in_sizes, int n_in,
                              void* d_out, int out_size, void* d_ws, size_t ws_size,
                              hipStream_t stream) {
  const float* x   = (const float*)d_in[0];
  const float* mod = (const float*)d_in[1];
  const float* W   = (const float*)d_in[2];
  float* out = (float*)d_out;

  const int D = 1024;
  const int Bn = in_sizes[0] / D;  // 8192
  const int Cn = in_sizes[2] / D;  // 4096

  bf16_t* a  = (bf16_t*)d_ws;                                      // B*D bf16 = 16 MB
  bf16_t* Wb = (bf16_t*)((char*)d_ws + (size_t)Bn * D * sizeof(bf16_t));  // C*D bf16 = 8 MB

  att_scale_kernel<<<Bn, 256, 0, stream>>>(x, mod, a, D);
  cast_w_kernel<<<((size_t)Cn * D) / (256 * 8), 256, 0, stream>>>(W, Wb);
  gemm_bt_kernel<<<dim3(Cn / BN, Bn / BM), 256, 0, stream>>>(a, Wb, out, Bn, Cn, D);
}

// Round 2
// 266.465 us; speedup vs baseline: 1.0449x; 1.0449x over previous
//
#include <hip/hip_runtime.h>
#include <hip/hip_bf16.h>
#include <cstdint>
#include <cstddef>

typedef __bf16 bf16_t;
typedef __bf16 bf16x8 __attribute__((ext_vector_type(8)));
typedef __bf16 bf16x4 __attribute__((ext_vector_type(4)));
typedef float  f32x4  __attribute__((ext_vector_type(4)));

#define BM 128
#define BN 128
#define BK 64

// ---------------------------------------------------------------------------
// Kernel 1: per-row softmax(mod) + 1, multiply by x, emit bf16.
// One block (256 threads) per row of D=1024; each thread owns 4 elements.
// ---------------------------------------------------------------------------
__global__ void att_scale_kernel(const float* __restrict__ x,
                                 const float* __restrict__ mod,
                                 bf16_t* __restrict__ a, int D) {
  const int b = blockIdx.x;
  const int t = threadIdx.x;
  const size_t row = (size_t)b * D;

  float4 mv = ((const float4*)(mod + row))[t];
  float mx = fmaxf(fmaxf(mv.x, mv.y), fmaxf(mv.z, mv.w));
#pragma unroll
  for (int o = 32; o > 0; o >>= 1) mx = fmaxf(mx, __shfl_xor(mx, o));

  __shared__ float redmax[4];
  __shared__ float redsum[4];
  const int wave = t >> 6, lane = t & 63;
  if (lane == 0) redmax[wave] = mx;
  __syncthreads();
  mx = fmaxf(fmaxf(redmax[0], redmax[1]), fmaxf(redmax[2], redmax[3]));

  float4 e;
  e.x = __expf(mv.x - mx); e.y = __expf(mv.y - mx);
  e.z = __expf(mv.z - mx); e.w = __expf(mv.w - mx);
  float s = (e.x + e.y) + (e.z + e.w);
#pragma unroll
  for (int o = 32; o > 0; o >>= 1) s += __shfl_xor(s, o);
  if (lane == 0) redsum[wave] = s;
  __syncthreads();
  s = (redsum[0] + redsum[1]) + (redsum[2] + redsum[3]);

  const float inv = 1.0f / s;
  float4 xv = ((const float4*)(x + row))[t];
  bf16x4 o4;
  o4[0] = (bf16_t)((e.x * inv + 1.0f) * xv.x);
  o4[1] = (bf16_t)((e.y * inv + 1.0f) * xv.y);
  o4[2] = (bf16_t)((e.z * inv + 1.0f) * xv.z);
  o4[3] = (bf16_t)((e.w * inv + 1.0f) * xv.w);
  *((bf16x4*)(a + row) + t) = o4;
}

// ---------------------------------------------------------------------------
// Kernel 2: fp32 -> bf16 cast of W (C*D elements), 8 per thread.
// ---------------------------------------------------------------------------
__global__ void cast_w_kernel(const float* __restrict__ W,
                              bf16_t* __restrict__ Wb) {
  const size_t i = ((size_t)blockIdx.x * blockDim.x + threadIdx.x) * 8;
  float4 u = *(const float4*)(W + i);
  float4 v = *(const float4*)(W + i + 4);
  bf16x8 o;
  o[0] = (bf16_t)u.x; o[1] = (bf16_t)u.y; o[2] = (bf16_t)u.z; o[3] = (bf16_t)u.w;
  o[4] = (bf16_t)v.x; o[5] = (bf16_t)v.y; o[6] = (bf16_t)v.z; o[7] = (bf16_t)v.w;
  *(bf16x8*)(Wb + i) = o;
}

// ---------------------------------------------------------------------------
// Kernel 3: bf16 GEMM, C[m][n] = sum_k A[m][k] * B[n][k]   (B^T-input GEMM)
// A: (M,K) row-major bf16, B: (N,K) row-major bf16, C: (M,N) fp32.
// 128x128 tile, BK=64, global_load_lds width=16, XOR-swizzled LDS layout:
// element (row, c8) of the tile lives at LDS column (c8 ^ (row&7)).
// Swizzle is applied on the GLOBAL address at staging time (free), and on the
// column index at read time -> ds_read_b128 is bank-conflict-free (2-way max).
// ---------------------------------------------------------------------------
__global__ __launch_bounds__(256) void gemm_bt_kernel(
    const bf16_t* __restrict__ A, const bf16_t* __restrict__ B,
    float* __restrict__ C, int M, int N, int K) {
  __shared__ __align__(16) bf16_t As[BM * BK];  // 16 KB
  __shared__ __align__(16) bf16_t Bs[BN * BK];  // 16 KB

  const int tid  = threadIdx.x;
  const int wave = tid >> 6;
  const int lane = tid & 63;
  const int quad = lane >> 4;
  const int l16  = lane & 15;

  const int m0 = blockIdx.y * BM;
  const int n0 = blockIdx.x * BN;
  const int wm = wave & 1;   // wave row (0..1) -> 64 rows of M
  const int wn = wave >> 1;  // wave col (0..1) -> 64 cols of N

  f32x4 acc[4][4];
#pragma unroll
  for (int i = 0; i < 4; i++)
#pragma unroll
    for (int j = 0; j < 4; j++) acc[i][j] = (f32x4){0.f, 0.f, 0.f, 0.f};

  // Staging: instr i, thread tid covers LDS slot s = i*256 + tid
  //   (row = s>>3, lds_col8 = s&7). Stored element is global column
  //   (lds_col8 ^ (row&7)) -> XOR applied to the global source address.
  const int rowA    = tid >> 3;
  const int col8swz = (tid & 7) ^ (rowA & 7);   // i*32 doesn't change row&7
  const bf16_t* aptr = A + (size_t)(m0 + rowA) * K + col8swz * 8;
  const bf16_t* bptr = B + (size_t)(n0 + rowA) * K + col8swz * 8;

  for (int k0 = 0; k0 < K; k0 += BK) {
#pragma unroll
    for (int i = 0; i < 4; i++) {
      __builtin_amdgcn_global_load_lds(
          (const __attribute__((address_space(1))) void*)(aptr + (size_t)(i * 32) * K + k0),
          (__attribute__((address_space(3))) void*)(As + (i * 256 + wave * 64) * 8),
          16, 0, 0);
    }
#pragma unroll
    for (int i = 0; i < 4; i++) {
      __builtin_amdgcn_global_load_lds(
          (const __attribute__((address_space(1))) void*)(bptr + (size_t)(i * 32) * K + k0),
          (__attribute__((address_space(3))) void*)(Bs + (i * 256 + wave * 64) * 8),
          16, 0, 0);
    }
    __syncthreads();

#pragma unroll
    for (int kt = 0; kt < 2; kt++) {
      bf16x8 af[4], bf[4];
#pragma unroll
      for (int i = 0; i < 4; i++) {
        const int r = wm * 64 + i * 16 + l16;
        const int c8 = ((kt << 2) | quad) ^ (l16 & 7);   // r&7 == l16&7
        af[i] = *(const bf16x8*)&As[r * BK + c8 * 8];
      }
#pragma unroll
      for (int j = 0; j < 4; j++) {
        const int r = wn * 64 + j * 16 + l16;
        const int c8 = ((kt << 2) | quad) ^ (l16 & 7);
        bf[j] = *(const bf16x8*)&Bs[r * BK + c8 * 8];
      }
#pragma unroll
      for (int i = 0; i < 4; i++)
#pragma unroll
        for (int j = 0; j < 4; j++)
          acc[i][j] = __builtin_amdgcn_mfma_f32_16x16x32_bf16(af[i], bf[j], acc[i][j], 0, 0, 0);
    }
    __syncthreads();
  }

  // Epilogue: C/D layout (16x16): col = lane&15, row = quad*4 + reg.
#pragma unroll
  for (int i = 0; i < 4; i++) {
    const int mg = m0 + wm * 64 + i * 16 + quad * 4;
#pragma unroll
    for (int j = 0; j < 4; j++) {
      const int ng = n0 + wn * 64 + j * 16 + l16;
#pragma unroll
      for (int r = 0; r < 4; r++) {
        C[(size_t)(mg + r) * N + ng] = acc[i][j][r];
      }
    }
  }
}

// ---------------------------------------------------------------------------
extern "C" void kernel_launch(void* const* d_in, const int* in_sizes, int n_in,
                              void* d_out, int out_size, void* d_ws, size_t ws_size,
                              hipStream_t stream) {
  const float* x   = (const float*)d_in[0];
  const float* mod = (const float*)d_in[1];
  const float* W   = (const float*)d_in[2];
  float* out = (float*)d_out;

  const int D = 1024;
  const int Bn = in_sizes[0] / D;  // 8192
  const int Cn = in_sizes[2] / D;  // 4096

  bf16_t* a  = (bf16_t*)d_ws;                                      // B*D bf16 = 16 MB
  bf16_t* Wb = (bf16_t*)((char*)d_ws + (size_t)Bn * D * sizeof(bf16_t));  // C*D bf16 = 8 MB

  att_scale_kernel<<<Bn, 256, 0, stream>>>(x, mod, a, D);
  cast_w_kernel<<<((size_t)Cn * D) / (256 * 8), 256, 0, stream>>>(W, Wb);
  gemm_bt_kernel<<<dim3(Cn / BN, Bn / BM), 256, 0, stream>>>(a, Wb, out, Bn, Cn, D);
}